// Round 1
// baseline (8804.816 us; speedup 1.0000x reference)
//
#include <hip/hip_runtime.h>

using u16 = unsigned short;
using u32 = unsigned int;

typedef short bf16x8 __attribute__((ext_vector_type(8)));
typedef float f32x4 __attribute__((ext_vector_type(4)));

__device__ __forceinline__ float bflo(u32 u) { return __uint_as_float(u << 16); }
__device__ __forceinline__ float bfhi(u32 u) { return __uint_as_float(u & 0xffff0000u); }
__device__ __forceinline__ float b2f(u16 u) { return __uint_as_float(((u32)u) << 16); }
__device__ __forceinline__ u16 f2bf(float f) {
  u32 u = __float_as_uint(f);
  u32 r = (u + 0x7fffu + ((u >> 16) & 1u)) >> 16;
  return (u16)r;
}

// ---------------------------------------------------------------- convert x -> bf16
__global__ __launch_bounds__(256) void f32_to_bf16_k(const float* __restrict__ in,
                                                     u16* __restrict__ out, int n4) {
  int i = blockIdx.x * 256 + threadIdx.x;
  if (i >= n4) return;
  float4 v = ((const float4*)in)[i];
  ushort4 o;
  o.x = f2bf(v.x); o.y = f2bf(v.y); o.z = f2bf(v.z); o.w = f2bf(v.w);
  ((ushort4*)out)[i] = o;
}

// ---------------------------------------------------------------- transpose f32 [Rr,Cc] -> bf16 [Cc,Rr]
__global__ __launch_bounds__(256) void transpose_to_bf16(const float* __restrict__ in,
                                                         u16* __restrict__ out,
                                                         int Rr, int Cc) {
  __shared__ float tile[32][33];
  const int tx = threadIdx.x;   // 32
  const int ty = threadIdx.y;   // 8
  const int r0 = blockIdx.y << 5;
  const int c0 = blockIdx.x << 5;
#pragma unroll
  for (int i = 0; i < 4; ++i)
    tile[ty + 8 * i][tx] = in[(size_t)(r0 + ty + 8 * i) * Cc + c0 + tx];
  __syncthreads();
#pragma unroll
  for (int i = 0; i < 4; ++i)
    out[(size_t)(c0 + ty + 8 * i) * Rr + r0 + tx] = f2bf(tile[tx][ty + 8 * i]);
}

// ---------------------------------------------------------------- bf16 MFMA GEMM
// C[M,N] = A[M,K] * Bt[N,K]^T.  Block 256 thr (4 waves), tile 64x64, BK=32.
// Wave w computes rows [w*16, w*16+16) x 64 cols via 4x mfma_f32_16x16x32_bf16.
// A-frag: m=lane&15, k=(lane>>4)*8+j ; B-frag: n=lane&15, same k ; C/D: col=lane&15, row=(lane>>4)*4+reg.
#define LDT 40   // padded LDS row stride (bf16 elems): 80B keeps b128 16B-aligned, ~2-way banks
__global__ __launch_bounds__(256) void gemm_bf16(const u16* __restrict__ A,
                                                 const u16* __restrict__ Bt,
                                                 void* __restrict__ Cv,
                                                 int M, int N, int K, int out_bf16) {
  __shared__ u16 a_t[64 * LDT];
  __shared__ u16 b_t[64 * LDT];
  const int tid = threadIdx.x;
  const int wave = tid >> 6;
  const int lane = tid & 63;
  const int quad = lane >> 4;
  const int l16 = lane & 15;
  const int m0 = blockIdx.y << 6;
  const int n0 = blockIdx.x << 6;

  const int srow = tid >> 2;          // 0..63 staging row
  const int scol = (tid & 3) << 3;    // 0,8,16,24
  const u16* Ap = A + (size_t)(m0 + srow) * K + scol;
  const u16* Bp = Bt + (size_t)(n0 + srow) * K + scol;
  u16* aw = &a_t[srow * LDT + scol];
  u16* bw = &b_t[srow * LDT + scol];

  f32x4 acc0 = {0.f, 0.f, 0.f, 0.f}, acc1 = acc0, acc2 = acc0, acc3 = acc0;

  const u16* afp = &a_t[(wave * 16 + l16) * LDT + quad * 8];
  const u16* bfp = &b_t[l16 * LDT + quad * 8];

  for (int k0 = 0; k0 < K; k0 += 32) {
    uint4 av = *(const uint4*)Ap;
    uint4 bv = *(const uint4*)Bp;
    __syncthreads();
    *(uint4*)aw = av;
    *(uint4*)bw = bv;
    __syncthreads();
    bf16x8 af = *(const bf16x8*)afp;
    bf16x8 b0 = *(const bf16x8*)(bfp);
    bf16x8 b1 = *(const bf16x8*)(bfp + 16 * LDT);
    bf16x8 b2 = *(const bf16x8*)(bfp + 32 * LDT);
    bf16x8 b3 = *(const bf16x8*)(bfp + 48 * LDT);
    acc0 = __builtin_amdgcn_mfma_f32_16x16x32_bf16(af, b0, acc0, 0, 0, 0);
    acc1 = __builtin_amdgcn_mfma_f32_16x16x32_bf16(af, b1, acc1, 0, 0, 0);
    acc2 = __builtin_amdgcn_mfma_f32_16x16x32_bf16(af, b2, acc2, 0, 0, 0);
    acc3 = __builtin_amdgcn_mfma_f32_16x16x32_bf16(af, b3, acc3, 0, 0, 0);
    Ap += 32; Bp += 32;
  }

  const int crow = m0 + wave * 16 + quad * 4;
  const int ccol = n0 + l16;
  if (out_bf16) {
    u16* C = (u16*)Cv;
#pragma unroll
    for (int r = 0; r < 4; ++r) {
      size_t base = (size_t)(crow + r) * N + ccol;
      C[base] = f2bf(acc0[r]);
      C[base + 16] = f2bf(acc1[r]);
      C[base + 32] = f2bf(acc2[r]);
      C[base + 48] = f2bf(acc3[r]);
    }
  } else {
    float* C = (float*)Cv;
#pragma unroll
    for (int r = 0; r < 4; ++r) {
      size_t base = (size_t)(crow + r) * N + ccol;
      C[base] = acc0[r];
      C[base + 16] = acc1[r];
      C[base + 32] = acc2[r];
      C[base + 48] = acc3[r];
    }
  }
}

// ---------------------------------------------------------------- RoPE+scale on K (layout-preserving [b,s,k,h])
__global__ __launch_bounds__(256) void rope_k_kernel(const u16* __restrict__ kf,
                                                     u16* __restrict__ kt,
                                                     const float* __restrict__ sinT,
                                                     const float* __restrict__ cosT) {
  int idx = blockIdx.x * 256 + threadIdx.x;   // B*S*K*H = 4,194,304
  int h = idx & 127;
  int s = (idx >> 10) & 2047;
  float t0 = b2f(kf[idx]);
  float tp = b2f(kf[(h < 64) ? idx + 64 : idx - 64]);
  float rot = (h < 64) ? -tp : tp;
  float o = (t0 * cosT[(s << 7) + h] + rot * sinT[(s << 7) + h]) * 0.08838834764831845f;
  kt[idx] = f2bf(o);
}

// ---------------------------------------------------------------- flash attention
// 1 wave = 1 query row (rope applied on q load), 4 rows/block, causal chunks of 64 kv.
// K chunk in LDS as [t][h] bf16, XOR-swizzled uint2 cells; V chunk transposed [h][j] bf16 swizzled.
__global__ __launch_bounds__(256) void attn_kernel(const u16* __restrict__ qf,
                                                   const u16* __restrict__ kt,
                                                   const u16* __restrict__ vf,
                                                   const float* __restrict__ sinT,
                                                   const float* __restrict__ cosT,
                                                   u16* __restrict__ y2) {
  __shared__ __align__(16) float q_lds[4][128];
  __shared__ uint2 kl[64][32];   // [t][group of 4 h], cell index ^ (t&31)
  __shared__ uint2 vl[128][16];  // [h][group of 4 j], cell index ^ vswz(h)

  const int tid = threadIdx.x;
  const int wave = tid >> 6;
  const int lane = tid & 63;
  const int bx = blockIdx.x;    // 0..511 row blocks
  const int head = blockIdx.y;  // 0..31 (= r*8 + k)
  const int b = blockIdx.z;
  const int kh = head & 7;
  const int row0 = bx << 2;
  const int s = row0 + wave;

  { // load + rope q row into LDS (all lanes of wave share it)
    size_t qbase = ((size_t)(b * 2048 + s)) * 4096 + head * 128;
    float f0 = b2f(qf[qbase + lane]);
    float f1 = b2f(qf[qbase + 64 + lane]);
    const float* sp = sinT + s * 128;
    const float* cp = cosT + s * 128;
    q_lds[wave][lane] = f0 * cp[lane] - f1 * sp[lane];
    q_lds[wave][64 + lane] = f1 * cp[64 + lane] + f0 * sp[64 + lane];
  }

  float run_m = -1e30f, run_l = 0.0f, acc0 = 0.0f, acc1 = 0.0f;

  const int tt_l = tid >> 4;        // 0..15
  const int h0 = (tid & 15) << 3;   // 0..120 step 8
  const int g0 = h0 >> 2;           // even
  const int nchunk = (bx >> 4) + 1;
  const size_t brow = (size_t)b * 2048;

  for (int c = 0; c < nchunk; ++c) {
    const int tbase = c << 6;
    __syncthreads();
#pragma unroll
    for (int i = 0; i < 4; ++i) {
      int tt = (i << 4) + tt_l;
      size_t gaddr = ((brow + tbase + tt) * 8 + kh) * 128 + h0;
      uint4 kw = *(const uint4*)(kt + gaddr);
      uint4 vw = *(const uint4*)(vf + gaddr);
      int xs = tt & 31;
      kl[tt][g0 ^ xs] = make_uint2(kw.x, kw.y);
      kl[tt][(g0 + 1) ^ xs] = make_uint2(kw.z, kw.w);
      const u16* vwp = (const u16*)&vw;
      int jg = tt >> 2, jb = tt & 3;
#pragma unroll
      for (int u = 0; u < 8; ++u) {
        int hh = h0 + u;
        int vsw = (hh + (hh >> 3)) & 15;
        ((u16*)&vl[hh][jg ^ vsw])[jb] = vwp[u];
      }
    }
    __syncthreads();

    const int t = tbase + lane;
    const bool valid = (t <= s);
    float d0 = 0.f, d1 = 0.f, d2 = 0.f, d3 = 0.f;
    const float4* q4 = (const float4*)q_lds[wave];
    const int xs = lane & 31;
#pragma unroll
    for (int g = 0; g < 32; ++g) {
      uint2 kv2 = kl[lane][g ^ xs];
      float4 qv = q4[g];
      d0 += bflo(kv2.x) * qv.x;
      d1 += bfhi(kv2.x) * qv.y;
      d2 += bflo(kv2.y) * qv.z;
      d3 += bfhi(kv2.y) * qv.w;
    }
    float sc = (d0 + d1) + (d2 + d3);
    sc = valid ? sc : -1e30f;
    float cm = sc;
#pragma unroll
    for (int off = 32; off; off >>= 1) cm = fmaxf(cm, __shfl_xor(cm, off));
    const float newm = fmaxf(run_m, cm);
    const float alpha = __expf(run_m - newm);
    const float p = valid ? __expf(sc - newm) : 0.0f;
    float ps = p;
#pragma unroll
    for (int off = 32; off; off >>= 1) ps += __shfl_xor(ps, off);
    run_l = run_l * alpha + ps;
    run_m = newm;
    acc0 *= alpha;
    acc1 *= alpha;

    const int vsa = (lane + (lane >> 3)) & 15;
    const int vsb = (vsa + 8) & 15;
#pragma unroll
    for (int jg = 0; jg < 16; ++jg) {
      uint2 va = vl[lane][jg ^ vsa];
      uint2 vb = vl[64 + lane][jg ^ vsb];
      float p0 = __shfl(p, (jg << 2) + 0);
      float p1 = __shfl(p, (jg << 2) + 1);
      float p2 = __shfl(p, (jg << 2) + 2);
      float p3 = __shfl(p, (jg << 2) + 3);
      acc0 += p0 * bflo(va.x) + p1 * bfhi(va.x) + p2 * bflo(va.y) + p3 * bfhi(va.y);
      acc1 += p0 * bflo(vb.x) + p1 * bfhi(vb.x) + p2 * bflo(vb.y) + p3 * bfhi(vb.y);
    }
  }

  const float inv_l = 1.0f / run_l;
  size_t ybase = ((size_t)(b * 2048 + s)) * 4096 + head * 128;
  y2[ybase + lane] = f2bf(acc0 * inv_l);
  y2[ybase + 64 + lane] = f2bf(acc1 * inv_l);
}

// ---------------------------------------------------------------- launch
extern "C" void kernel_launch(void* const* d_in, const int* in_sizes, int n_in,
                              void* d_out, int out_size, void* d_ws, size_t ws_size,
                              hipStream_t stream) {
  const float* x = (const float*)d_in[0];
  const float* wq = (const float*)d_in[1];
  const float* wk = (const float*)d_in[2];
  const float* wv = (const float*)d_in[3];
  const float* wo = (const float*)d_in[4];
  // d_in[5] = mask (causal, implemented directly)
  const float* sinT = (const float*)d_in[6];
  const float* cosT = (const float*)d_in[7];
  float* out = (float*)d_out;

  char* ws = (char*)d_ws;
  size_t off = 0;
  auto alloc = [&](size_t bytes) -> void* {
    void* p = ws + off;
    off += (bytes + 255) & ~(size_t)255;
    return p;
  };
  u16* xb  = (u16*)alloc(16777216ull * 2);  // x bf16 [4096,4096]
  u16* wqT = (u16*)alloc(16777216ull * 2);  // [4096(rkh),4096(d)]
  u16* wkT = (u16*)alloc(4194304ull * 2);   // [1024,4096]
  u16* wvT = (u16*)alloc(4194304ull * 2);
  u16* woT = (u16*)alloc(16777216ull * 2);  // [4096(d),4096(rkh)]
  u16* qf  = (u16*)alloc(16777216ull * 2);  // [b,s,(r,k,h)]
  u16* kf  = (u16*)alloc(4194304ull * 2);   // [b,s,(k,h)]
  u16* vf  = (u16*)alloc(4194304ull * 2);
  u16* ktb = (u16*)alloc(4194304ull * 2);   // roped+scaled k, same layout
  u16* y2  = (u16*)alloc(16777216ull * 2);  // [b,s,(r,k,h)]

  dim3 tb(32, 8);
  f32_to_bf16_k<<<dim3(16384), 256, 0, stream>>>(x, xb, 4194304);
  transpose_to_bf16<<<dim3(128, 128), tb, 0, stream>>>(wq, wqT, 4096, 4096);
  transpose_to_bf16<<<dim3(32, 128), tb, 0, stream>>>(wk, wkT, 4096, 1024);
  transpose_to_bf16<<<dim3(32, 128), tb, 0, stream>>>(wv, wvT, 4096, 1024);
  transpose_to_bf16<<<dim3(128, 128), tb, 0, stream>>>(wo, woT, 4096, 4096);

  gemm_bf16<<<dim3(64, 64), 256, 0, stream>>>(xb, wqT, qf, 4096, 4096, 4096, 1);
  gemm_bf16<<<dim3(16, 64), 256, 0, stream>>>(xb, wkT, kf, 4096, 1024, 4096, 1);
  gemm_bf16<<<dim3(16, 64), 256, 0, stream>>>(xb, wvT, vf, 4096, 1024, 4096, 1);

  rope_k_kernel<<<dim3(16384), 256, 0, stream>>>(kf, ktb, sinT, cosT);

  attn_kernel<<<dim3(512, 32, 2), 256, 0, stream>>>(qf, ktb, vf, sinT, cosT, y2);

  gemm_bf16<<<dim3(64, 64), 256, 0, stream>>>(y2, woT, out, 4096, 4096, 4096, 0);
}

// Round 2
// 1508.684 us; speedup vs baseline: 5.8361x; 5.8361x over previous
//
#include <hip/hip_runtime.h>

using u16 = unsigned short;
using u32 = unsigned int;

typedef short bf16x8 __attribute__((ext_vector_type(8)));
typedef float f32x4 __attribute__((ext_vector_type(4)));

__device__ __forceinline__ float bflo(u32 u) { return __uint_as_float(u << 16); }
__device__ __forceinline__ float bfhi(u32 u) { return __uint_as_float(u & 0xffff0000u); }
__device__ __forceinline__ float b2f(u16 u) { return __uint_as_float(((u32)u) << 16); }
__device__ __forceinline__ u16 f2bf(float f) {
  u32 u = __float_as_uint(f);
  u32 r = (u + 0x7fffu + ((u >> 16) & 1u)) >> 16;
  return (u16)r;
}
__device__ __forceinline__ u16 f2bf_trunc(float f) {  // cheap truncate (P probs only)
  return (u16)(__float_as_uint(f) >> 16);
}

// ---------------------------------------------------------------- convert x -> bf16
__global__ __launch_bounds__(256) void f32_to_bf16_k(const float* __restrict__ in,
                                                     u16* __restrict__ out, int n4) {
  int i = blockIdx.x * 256 + threadIdx.x;
  if (i >= n4) return;
  float4 v = ((const float4*)in)[i];
  ushort4 o;
  o.x = f2bf(v.x); o.y = f2bf(v.y); o.z = f2bf(v.z); o.w = f2bf(v.w);
  ((ushort4*)out)[i] = o;
}

// ---------------------------------------------------------------- transpose f32 [Rr,Cc] -> bf16 [Cc,Rr]
__global__ __launch_bounds__(256) void transpose_to_bf16(const float* __restrict__ in,
                                                         u16* __restrict__ out,
                                                         int Rr, int Cc) {
  __shared__ float tile[32][33];
  const int tx = threadIdx.x;   // 32
  const int ty = threadIdx.y;   // 8
  const int r0 = blockIdx.y << 5;
  const int c0 = blockIdx.x << 5;
#pragma unroll
  for (int i = 0; i < 4; ++i)
    tile[ty + 8 * i][tx] = in[(size_t)(r0 + ty + 8 * i) * Cc + c0 + tx];
  __syncthreads();
#pragma unroll
  for (int i = 0; i < 4; ++i)
    out[(size_t)(c0 + ty + 8 * i) * Rr + r0 + tx] = f2bf(tile[tx][ty + 8 * i]);
}

// ---------------------------------------------------------------- bf16 MFMA GEMM (64x64 tile)
#define LDT 40
__global__ __launch_bounds__(256) void gemm_bf16(const u16* __restrict__ A,
                                                 const u16* __restrict__ Bt,
                                                 void* __restrict__ Cv,
                                                 int M, int N, int K, int out_bf16) {
  __shared__ u16 a_t[64 * LDT];
  __shared__ u16 b_t[64 * LDT];
  const int tid = threadIdx.x;
  const int wave = tid >> 6;
  const int lane = tid & 63;
  const int quad = lane >> 4;
  const int l16 = lane & 15;
  const int m0 = blockIdx.y << 6;
  const int n0 = blockIdx.x << 6;

  const int srow = tid >> 2;
  const int scol = (tid & 3) << 3;
  const u16* Ap = A + (size_t)(m0 + srow) * K + scol;
  const u16* Bp = Bt + (size_t)(n0 + srow) * K + scol;
  u16* aw = &a_t[srow * LDT + scol];
  u16* bw = &b_t[srow * LDT + scol];

  f32x4 acc0 = {0.f, 0.f, 0.f, 0.f}, acc1 = acc0, acc2 = acc0, acc3 = acc0;

  const u16* afp = &a_t[(wave * 16 + l16) * LDT + quad * 8];
  const u16* bfp = &b_t[l16 * LDT + quad * 8];

  for (int k0 = 0; k0 < K; k0 += 32) {
    uint4 av = *(const uint4*)Ap;
    uint4 bv = *(const uint4*)Bp;
    __syncthreads();
    *(uint4*)aw = av;
    *(uint4*)bw = bv;
    __syncthreads();
    bf16x8 af = *(const bf16x8*)afp;
    bf16x8 b0 = *(const bf16x8*)(bfp);
    bf16x8 b1 = *(const bf16x8*)(bfp + 16 * LDT);
    bf16x8 b2 = *(const bf16x8*)(bfp + 32 * LDT);
    bf16x8 b3 = *(const bf16x8*)(bfp + 48 * LDT);
    acc0 = __builtin_amdgcn_mfma_f32_16x16x32_bf16(af, b0, acc0, 0, 0, 0);
    acc1 = __builtin_amdgcn_mfma_f32_16x16x32_bf16(af, b1, acc1, 0, 0, 0);
    acc2 = __builtin_amdgcn_mfma_f32_16x16x32_bf16(af, b2, acc2, 0, 0, 0);
    acc3 = __builtin_amdgcn_mfma_f32_16x16x32_bf16(af, b3, acc3, 0, 0, 0);
    Ap += 32; Bp += 32;
  }

  const int crow = m0 + wave * 16 + quad * 4;
  const int ccol = n0 + l16;
  if (out_bf16) {
    u16* C = (u16*)Cv;
#pragma unroll
    for (int r = 0; r < 4; ++r) {
      size_t base = (size_t)(crow + r) * N + ccol;
      C[base] = f2bf(acc0[r]);
      C[base + 16] = f2bf(acc1[r]);
      C[base + 32] = f2bf(acc2[r]);
      C[base + 48] = f2bf(acc3[r]);
    }
  } else {
    float* C = (float*)Cv;
#pragma unroll
    for (int r = 0; r < 4; ++r) {
      size_t base = (size_t)(crow + r) * N + ccol;
      C[base] = acc0[r];
      C[base + 16] = acc1[r];
      C[base + 32] = acc2[r];
      C[base + 48] = acc3[r];
    }
  }
}

// ---------------------------------------------------------------- RoPE+scale on K ([b,s,k,h] preserved)
__global__ __launch_bounds__(256) void rope_k_kernel(const u16* __restrict__ kf,
                                                     u16* __restrict__ kt,
                                                     const float* __restrict__ sinT,
                                                     const float* __restrict__ cosT) {
  int idx = blockIdx.x * 256 + threadIdx.x;   // B*S*K*H = 4,194,304
  int h = idx & 127;
  int s = (idx >> 10) & 2047;
  float t0 = b2f(kf[idx]);
  float tp = b2f(kf[(h < 64) ? idx + 64 : idx - 64]);
  float rot = (h < 64) ? -tp : tp;
  float o = (t0 * cosT[(s << 7) + h] + rot * sinT[(s << 7) + h]) * 0.08838834764831845f;
  kt[idx] = f2bf(o);
}

// ---------------------------------------------------------------- transpose V: [b,t,kh,h] -> [b,kh,h,t]
__global__ __launch_bounds__(256) void transpose_v(const u16* __restrict__ vf,
                                                   u16* __restrict__ vtg) {
  __shared__ u16 tile[32][34];
  const int tx = threadIdx.x;   // 32
  const int ty = threadIdx.y;   // 8
  const int t0 = blockIdx.x << 5;
  const int h0 = blockIdx.y << 5;
  const int plane = blockIdx.z;     // b*8+kh
  const int b = plane >> 3, kh = plane & 7;
#pragma unroll
  for (int i = 0; i < 4; ++i) {
    int t = t0 + ty + 8 * i;
    tile[ty + 8 * i][tx] = vf[((size_t)(b * 2048 + t) * 8 + kh) * 128 + h0 + tx];
  }
  __syncthreads();
#pragma unroll
  for (int i = 0; i < 4; ++i)
    vtg[((size_t)plane * 128 + h0 + ty + 8 * i) * 2048 + t0 + tx] = tile[tx][ty + 8 * i];
}

// ---------------------------------------------------------------- MFMA flash attention
// grid (32 qtiles, 32 heads, 2 b), block 256 (4 waves). Wave w: q rows [qbase+16w, +16).
// KV chunks of 64. K LDS [t][h] pad 136; V^T LDS [h][t] pad 72; P per-wave [m][t] pad 72.
#define KP 136
#define TP 72
__global__ __launch_bounds__(256, 3) void attn_mfma(const u16* __restrict__ qf,
                                                    const u16* __restrict__ kt,
                                                    const u16* __restrict__ vtg,
                                                    const float* __restrict__ sinT,
                                                    const float* __restrict__ cosT,
                                                    u16* __restrict__ y2) {
  __shared__ u16 kl[64 * KP];        // 17408 B
  __shared__ u16 vt[128 * TP];       // 18432 B
  __shared__ u16 pl[4 * 16 * TP];    //  9216 B
  const int tid = threadIdx.x;
  const int wave = tid >> 6;
  const int lane = tid & 63;
  const int quad = lane >> 4;
  const int l16 = lane & 15;
  const int qt = 31 - blockIdx.x;    // heaviest tiles launch first
  const int head = blockIdx.y;
  const int b = blockIdx.z;
  const int kh = head & 7;
  const int qbase = qt << 6;
  const int srow = qbase + wave * 16 + l16;   // A-frag row for this lane

  // ---- load Q rows + RoPE -> 4 A-fragments (k-step kk covers h = kk*32 + quad*8 + j)
  bf16x8 qfrag[4];
  {
    size_t base = ((size_t)(b * 2048 + srow)) * 4096 + (size_t)head * 128;
    float qv[32];
#pragma unroll
    for (int kk = 0; kk < 4; ++kk) {
      uint4 w = *(const uint4*)(qf + base + kk * 32 + quad * 8);
      const u16* ws = (const u16*)&w;
#pragma unroll
      for (int j = 0; j < 8; ++j) qv[kk * 8 + j] = b2f(ws[j]);
    }
    const float* cp = cosT + (size_t)srow * 128;
    const float* sp = sinT + (size_t)srow * 128;
#pragma unroll
    for (int kk = 0; kk < 2; ++kk) {
      int hb = kk * 32 + quad * 8;
      float4 c0 = *(const float4*)(cp + hb);
      float4 c1 = *(const float4*)(cp + hb + 4);
      float4 s0 = *(const float4*)(sp + hb);
      float4 s1 = *(const float4*)(sp + hb + 4);
      float cc[8] = {c0.x, c0.y, c0.z, c0.w, c1.x, c1.y, c1.z, c1.w};
      float ss[8] = {s0.x, s0.y, s0.z, s0.w, s1.x, s1.y, s1.z, s1.w};
      // cos/sin tables duplicate halves: table[h+64] == table[h]
#pragma unroll
      for (int j = 0; j < 8; ++j) {
        float a = qv[kk * 8 + j];
        float bb = qv[(kk + 2) * 8 + j];
        qfrag[kk][j] = (short)f2bf(a * cc[j] - bb * ss[j]);
        qfrag[kk + 2][j] = (short)f2bf(bb * cc[j] + a * ss[j]);
      }
    }
  }

  f32x4 o[8];
#pragma unroll
  for (int i = 0; i < 8; ++i) o[i] = (f32x4){0.f, 0.f, 0.f, 0.f};
  float run_m[4] = {-1e30f, -1e30f, -1e30f, -1e30f};
  float run_l[4] = {0.f, 0.f, 0.f, 0.f};

  const int kst = tid >> 4;            // K stage: t row 0..15 (+16i)
  const int ksh = (tid & 15) << 3;     // K stage: h offset
  const int vst = (tid & 7) << 3;      // V stage: t offset
  const int vsh = tid >> 3;            // V stage: h row 0..31 (+32i)
  const size_t kbase0 = ((size_t)(b * 2048) * 8 + kh) * 128;
  const size_t vbase0 = ((size_t)(b * 8 + kh)) * 128 * 2048;
  u16* plw = pl + wave * 16 * TP;

  for (int c = 0; c <= qt; ++c) {
    __syncthreads();
    // stage K chunk [64][128]
#pragma unroll
    for (int i = 0; i < 4; ++i) {
      int tt = kst + i * 16;
      uint4 w = *(const uint4*)(kt + kbase0 + (size_t)(c * 64 + tt) * 1024 + ksh);
      *(uint4*)(kl + tt * KP + ksh) = w;
    }
    // stage V^T chunk [128][64]
#pragma unroll
    for (int i = 0; i < 4; ++i) {
      int hh = vsh + i * 32;
      uint4 w = *(const uint4*)(vtg + vbase0 + (size_t)hh * 2048 + c * 64 + vst);
      *(uint4*)(vt + hh * TP + vst) = w;
    }
    __syncthreads();

    // ---- QK^T : 4 n-tiles of 16 kv positions
    f32x4 s[4];
#pragma unroll
    for (int nt = 0; nt < 4; ++nt) {
      s[nt] = (f32x4){0.f, 0.f, 0.f, 0.f};
#pragma unroll
      for (int kk = 0; kk < 4; ++kk) {
        bf16x8 bf = *(const bf16x8*)(kl + (nt * 16 + l16) * KP + kk * 32 + quad * 8);
        s[nt] = __builtin_amdgcn_mfma_f32_16x16x32_bf16(qfrag[kk], bf, s[nt], 0, 0, 0);
      }
    }
    // ---- causal mask on the diagonal chunk
    if (c == qt) {
      int tcol = l16;  // + nt*16, local
      int rbase = wave * 16 + quad * 4;
#pragma unroll
      for (int nt = 0; nt < 4; ++nt)
#pragma unroll
        for (int r = 0; r < 4; ++r)
          if (nt * 16 + tcol > rbase + r) s[nt][r] = -1e30f;
    }
    // ---- online softmax (row = (quad,reg); reduce across l16 lanes)
    float p[4][4];
#pragma unroll
    for (int r = 0; r < 4; ++r) {
      float cm = fmaxf(fmaxf(s[0][r], s[1][r]), fmaxf(s[2][r], s[3][r]));
#pragma unroll
      for (int off = 1; off < 16; off <<= 1) cm = fmaxf(cm, __shfl_xor(cm, off));
      float newm = fmaxf(run_m[r], cm);
      float alpha = __expf(run_m[r] - newm);
      float rs = 0.f;
#pragma unroll
      for (int nt = 0; nt < 4; ++nt) {
        float pv = __expf(s[nt][r] - newm);
        p[nt][r] = pv;
        rs += pv;
      }
#pragma unroll
      for (int off = 1; off < 16; off <<= 1) rs += __shfl_xor(rs, off);
      run_l[r] = run_l[r] * alpha + rs;
      run_m[r] = newm;
#pragma unroll
      for (int ht = 0; ht < 8; ++ht) o[ht][r] *= alpha;
    }
    // ---- P -> per-wave LDS [m][t] (bf16)
#pragma unroll
    for (int nt = 0; nt < 4; ++nt)
#pragma unroll
      for (int r = 0; r < 4; ++r)
        plw[(quad * 4 + r) * TP + nt * 16 + l16] = f2bf_trunc(p[nt][r]);
    // ---- PV : O[16 x 128] += P[16 x 64] * V[64 x 128]
#pragma unroll
    for (int kk = 0; kk < 2; ++kk) {
      bf16x8 af = *(const bf16x8*)(plw + l16 * TP + kk * 32 + quad * 8);
#pragma unroll
      for (int ht = 0; ht < 8; ++ht) {
        bf16x8 bf = *(const bf16x8*)(vt + (ht * 16 + l16) * TP + kk * 32 + quad * 8);
        o[ht] = __builtin_amdgcn_mfma_f32_16x16x32_bf16(af, bf, o[ht], 0, 0, 0);
      }
    }
  }

  // ---- epilogue: normalize + store (C layout: row=quad*4+r, col=ht*16+l16)
  float inv_l[4];
#pragma unroll
  for (int r = 0; r < 4; ++r) inv_l[r] = 1.0f / run_l[r];
#pragma unroll
  for (int r = 0; r < 4; ++r) {
    int row = qbase + wave * 16 + quad * 4 + r;
    size_t base = ((size_t)(b * 2048 + row)) * 4096 + (size_t)head * 128 + l16;
#pragma unroll
    for (int ht = 0; ht < 8; ++ht)
      y2[base + ht * 16] = f2bf(o[ht][r] * inv_l[r]);
  }
}

// ---------------------------------------------------------------- launch
extern "C" void kernel_launch(void* const* d_in, const int* in_sizes, int n_in,
                              void* d_out, int out_size, void* d_ws, size_t ws_size,
                              hipStream_t stream) {
  const float* x = (const float*)d_in[0];
  const float* wq = (const float*)d_in[1];
  const float* wk = (const float*)d_in[2];
  const float* wv = (const float*)d_in[3];
  const float* wo = (const float*)d_in[4];
  const float* sinT = (const float*)d_in[6];
  const float* cosT = (const float*)d_in[7];
  float* out = (float*)d_out;

  char* ws = (char*)d_ws;
  size_t off = 0;
  auto alloc = [&](size_t bytes) -> void* {
    void* p = ws + off;
    off += (bytes + 255) & ~(size_t)255;
    return p;
  };
  u16* xb  = (u16*)alloc(16777216ull * 2);
  u16* wqT = (u16*)alloc(16777216ull * 2);
  u16* wkT = (u16*)alloc(4194304ull * 2);
  u16* wvT = (u16*)alloc(4194304ull * 2);
  u16* woT = (u16*)alloc(16777216ull * 2);
  u16* qf  = (u16*)alloc(16777216ull * 2);
  u16* kf  = (u16*)alloc(4194304ull * 2);   // also reused as vtg after rope_k
  u16* vf  = (u16*)alloc(4194304ull * 2);
  u16* ktb = (u16*)alloc(4194304ull * 2);
  u16* y2  = (u16*)alloc(16777216ull * 2);

  dim3 tb(32, 8);
  f32_to_bf16_k<<<dim3(16384), 256, 0, stream>>>(x, xb, 4194304);
  transpose_to_bf16<<<dim3(128, 128), tb, 0, stream>>>(wq, wqT, 4096, 4096);
  transpose_to_bf16<<<dim3(32, 128), tb, 0, stream>>>(wk, wkT, 4096, 1024);
  transpose_to_bf16<<<dim3(32, 128), tb, 0, stream>>>(wv, wvT, 4096, 1024);
  transpose_to_bf16<<<dim3(128, 128), tb, 0, stream>>>(wo, woT, 4096, 4096);

  gemm_bf16<<<dim3(64, 64), 256, 0, stream>>>(xb, wqT, qf, 4096, 4096, 4096, 1);
  gemm_bf16<<<dim3(16, 64), 256, 0, stream>>>(xb, wkT, kf, 4096, 1024, 4096, 1);
  gemm_bf16<<<dim3(16, 64), 256, 0, stream>>>(xb, wvT, vf, 4096, 1024, 4096, 1);

  rope_k_kernel<<<dim3(16384), 256, 0, stream>>>(kf, ktb, sinT, cosT);

  u16* vtg = kf;  // kf dead after rope_k; reuse as V^T [b,kh,h,t]
  transpose_v<<<dim3(64, 4, 16), tb, 0, stream>>>(vf, vtg);

  attn_mfma<<<dim3(32, 32, 2), 256, 0, stream>>>(qf, ktb, vtg, sinT, cosT, y2);

  gemm_bf16<<<dim3(64, 64), 256, 0, stream>>>(y2, woT, out, 4096, 4096, 4096, 0);
}

// Round 3
// 1397.844 us; speedup vs baseline: 6.2989x; 1.0793x over previous
//
#include <hip/hip_runtime.h>

using u16 = unsigned short;
using u32 = unsigned int;

typedef short bf16x8 __attribute__((ext_vector_type(8)));
typedef float f32x4 __attribute__((ext_vector_type(4)));

__device__ __forceinline__ float bflo(u32 u) { return __uint_as_float(u << 16); }
__device__ __forceinline__ float bfhi(u32 u) { return __uint_as_float(u & 0xffff0000u); }
__device__ __forceinline__ float b2f(u16 u) { return __uint_as_float(((u32)u) << 16); }
__device__ __forceinline__ u16 f2bf(float f) {
  u32 u = __float_as_uint(f);
  u32 r = (u + 0x7fffu + ((u >> 16) & 1u)) >> 16;
  return (u16)r;
}
__device__ __forceinline__ u16 f2bf_trunc(float f) {  // cheap truncate (P probs only)
  return (u16)(__float_as_uint(f) >> 16);
}

// async global->LDS, 16B per lane. LDS dest is wave-uniform base + lane*16.
__device__ __forceinline__ void gl16(const u16* g, u16* l) {
  __builtin_amdgcn_global_load_lds((const __attribute__((address_space(1))) u32*)g,
                                   (__attribute__((address_space(3))) u32*)l, 16, 0, 0);
}

// ---------------------------------------------------------------- convert x -> bf16
__global__ __launch_bounds__(256) void f32_to_bf16_k(const float* __restrict__ in,
                                                     u16* __restrict__ out, int n4) {
  int i = blockIdx.x * 256 + threadIdx.x;
  if (i >= n4) return;
  float4 v = ((const float4*)in)[i];
  ushort4 o;
  o.x = f2bf(v.x); o.y = f2bf(v.y); o.z = f2bf(v.z); o.w = f2bf(v.w);
  ((ushort4*)out)[i] = o;
}

// ---------------------------------------------------------------- transpose f32 [Rr,Cc] -> bf16 [Cc,Rr]
__global__ __launch_bounds__(256) void transpose_to_bf16(const float* __restrict__ in,
                                                         u16* __restrict__ out,
                                                         int Rr, int Cc) {
  __shared__ float tile[32][33];
  const int tx = threadIdx.x;   // 32
  const int ty = threadIdx.y;   // 8
  const int r0 = blockIdx.y << 5;
  const int c0 = blockIdx.x << 5;
#pragma unroll
  for (int i = 0; i < 4; ++i)
    tile[ty + 8 * i][tx] = in[(size_t)(r0 + ty + 8 * i) * Cc + c0 + tx];
  __syncthreads();
#pragma unroll
  for (int i = 0; i < 4; ++i)
    out[(size_t)(c0 + ty + 8 * i) * Rr + r0 + tx] = f2bf(tile[tx][ty + 8 * i]);
}

// ---------------------------------------------------------------- m97-style 128x128 MFMA GEMM
// C[M,N] = A[M,K]*Bt[N,K]^T. Block 256 (4 waves, 2x2), wave = 64x64 (4x4 16-tiles), BK=32.
// LDS [128 rows][32 k] u16 unpadded; 16B chunk c stored at c ^ SWZ(row) (2-way banks on b128 reads).
// Staged via global_load_lds: lane slot = linear, swizzle folded into the GLOBAL address.
#define SWZ4(r) (((r) & 3) ^ (((r) >> 2) & 3))
__global__ __launch_bounds__(256) void gemm128(const u16* __restrict__ A,
                                               const u16* __restrict__ Bt,
                                               void* __restrict__ Cv,
                                               int M, int N, int K, int out_bf16) {
  __shared__ __align__(16) u16 a_t[128 * 32];
  __shared__ __align__(16) u16 b_t[128 * 32];
  const int tid = threadIdx.x;
  const int wave = tid >> 6;
  const int lane = tid & 63;
  const int quad = lane >> 4;
  const int l16 = lane & 15;
  const int wm = wave >> 1;
  const int wn = wave & 1;
  const int m0 = blockIdx.y << 7;
  const int n0 = blockIdx.x << 7;

  // staging: inst j covers rows j*64 + (tid>>2); thread supplies global chunk (tid&3)^SWZ(row)
  const int srow = tid >> 2;
  const int scg = ((tid & 3) ^ SWZ4(srow)) << 3;
  const u16* Ag0 = A + (size_t)(m0 + srow) * K + scg;
  const u16* Ag1 = A + (size_t)(m0 + 64 + srow) * K + scg;
  const u16* Bg0 = Bt + (size_t)(n0 + srow) * K + scg;
  const u16* Bg1 = Bt + (size_t)(n0 + 64 + srow) * K + scg;
  u16* al0 = a_t + wave * 512 + lane * 8;
  u16* al1 = a_t + 2048 + wave * 512 + lane * 8;
  u16* bl0 = b_t + wave * 512 + lane * 8;
  u16* bl1 = b_t + 2048 + wave * 512 + lane * 8;

  // fragment read pointers: row = (wm*64 + mt*16 + l16); chunk = quad ^ SWZ(l16) (mt-invariant)
  const int fsw = (quad ^ SWZ4(l16)) << 3;
  const u16* afp = a_t + (wm * 64 + l16) * 32 + fsw;
  const u16* bfp = b_t + (wn * 64 + l16) * 32 + fsw;

  f32x4 acc[4][4];
#pragma unroll
  for (int i = 0; i < 4; ++i)
#pragma unroll
    for (int j = 0; j < 4; ++j) acc[i][j] = (f32x4){0.f, 0.f, 0.f, 0.f};

  for (int k0 = 0; k0 < K; k0 += 32) {
    __syncthreads();
    gl16(Ag0 + k0, al0);
    gl16(Ag1 + k0, al1);
    gl16(Bg0 + k0, bl0);
    gl16(Bg1 + k0, bl1);
    __syncthreads();
    bf16x8 af[4], bf[4];
#pragma unroll
    for (int t = 0; t < 4; ++t) {
      af[t] = *(const bf16x8*)(afp + t * 512);
      bf[t] = *(const bf16x8*)(bfp + t * 512);
    }
#pragma unroll
    for (int mt = 0; mt < 4; ++mt)
#pragma unroll
      for (int nt = 0; nt < 4; ++nt)
        acc[mt][nt] = __builtin_amdgcn_mfma_f32_16x16x32_bf16(af[mt], bf[nt], acc[mt][nt], 0, 0, 0);
  }

  // epilogue: C row = m0+wm*64+mt*16+quad*4+r, col = n0+wn*64+nt*16+l16
  if (out_bf16) {
    u16* C = (u16*)Cv;
#pragma unroll
    for (int mt = 0; mt < 4; ++mt)
#pragma unroll
      for (int r = 0; r < 4; ++r) {
        size_t base = (size_t)(m0 + wm * 64 + mt * 16 + quad * 4 + r) * N + n0 + wn * 64 + l16;
#pragma unroll
        for (int nt = 0; nt < 4; ++nt) C[base + nt * 16] = f2bf(acc[mt][nt][r]);
      }
  } else {
    float* C = (float*)Cv;
#pragma unroll
    for (int mt = 0; mt < 4; ++mt)
#pragma unroll
      for (int r = 0; r < 4; ++r) {
        size_t base = (size_t)(m0 + wm * 64 + mt * 16 + quad * 4 + r) * N + n0 + wn * 64 + l16;
#pragma unroll
        for (int nt = 0; nt < 4; ++nt) C[base + nt * 16] = acc[mt][nt][r];
      }
  }
}

// ---------------------------------------------------------------- RoPE+scale on K
// kvf: [b*s][2048] (cols 0..1023 = K heads, 1024.. = V). out kt: [b*s][1024]
__global__ __launch_bounds__(256) void rope_k_kernel(const u16* __restrict__ kvf,
                                                     u16* __restrict__ kt,
                                                     const float* __restrict__ sinT,
                                                     const float* __restrict__ cosT) {
  int idx = blockIdx.x * 256 + threadIdx.x;   // B*S*K*H = 4,194,304
  int h = idx & 127;
  int s = (idx >> 10) & 2047;
  size_t src = (size_t)(idx >> 10) * 2048 + (idx & 1023);
  float t0 = b2f(kvf[src]);
  float tp = b2f(kvf[(h < 64) ? src + 64 : src - 64]);
  float rot = (h < 64) ? -tp : tp;
  float o = (t0 * cosT[(s << 7) + h] + rot * sinT[(s << 7) + h]) * 0.08838834764831845f;
  kt[idx] = f2bf(o);
}

// ---------------------------------------------------------------- transpose V: kvf[b,t,(1024+kh*128+h)] -> [b,kh,h,t]
__global__ __launch_bounds__(256) void transpose_v(const u16* __restrict__ kvf,
                                                   u16* __restrict__ vtg) {
  __shared__ u16 tile[32][34];
  const int tx = threadIdx.x;   // 32
  const int ty = threadIdx.y;   // 8
  const int t0 = blockIdx.x << 5;
  const int h0 = blockIdx.y << 5;
  const int plane = blockIdx.z;     // b*8+kh
  const int b = plane >> 3, kh = plane & 7;
#pragma unroll
  for (int i = 0; i < 4; ++i) {
    int t = t0 + ty + 8 * i;
    tile[ty + 8 * i][tx] = kvf[(size_t)(b * 2048 + t) * 2048 + 1024 + kh * 128 + h0 + tx];
  }
  __syncthreads();
#pragma unroll
  for (int i = 0; i < 4; ++i)
    vtg[((size_t)plane * 128 + h0 + ty + 8 * i) * 2048 + t0 + tx] = tile[tx][ty + 8 * i];
}

// ---------------------------------------------------------------- MFMA flash attention
// grid (32 qtiles, 32 heads, 2 b), block 256 (4 waves). Wave w: q rows [qbase+16w, +16).
// KV chunks of 64, register-prefetched one chunk ahead (latency-bound fix).
#define KP 136
#define TP 72
__global__ __launch_bounds__(256, 3) void attn_mfma(const u16* __restrict__ qf,
                                                    const u16* __restrict__ kt,
                                                    const u16* __restrict__ vtg,
                                                    const float* __restrict__ sinT,
                                                    const float* __restrict__ cosT,
                                                    u16* __restrict__ y2) {
  __shared__ u16 kl[64 * KP];        // 17408 B
  __shared__ u16 vt[128 * TP];       // 18432 B
  __shared__ u16 pl[4 * 16 * TP];    //  9216 B
  const int tid = threadIdx.x;
  const int wave = tid >> 6;
  const int lane = tid & 63;
  const int quad = lane >> 4;
  const int l16 = lane & 15;
  const int qt = 31 - blockIdx.x;    // heaviest tiles launch first
  const int head = blockIdx.y;
  const int b = blockIdx.z;
  const int kh = head & 7;
  const int qbase = qt << 6;
  const int srow = qbase + wave * 16 + l16;   // A-frag row for this lane

  // ---- load Q rows + RoPE -> 4 A-fragments
  bf16x8 qfrag[4];
  {
    size_t base = ((size_t)(b * 2048 + srow)) * 4096 + (size_t)head * 128;
    float qv[32];
#pragma unroll
    for (int kk = 0; kk < 4; ++kk) {
      uint4 w = *(const uint4*)(qf + base + kk * 32 + quad * 8);
      const u16* ws = (const u16*)&w;
#pragma unroll
      for (int j = 0; j < 8; ++j) qv[kk * 8 + j] = b2f(ws[j]);
    }
    const float* cp = cosT + (size_t)srow * 128;
    const float* sp = sinT + (size_t)srow * 128;
#pragma unroll
    for (int kk = 0; kk < 2; ++kk) {
      int hb = kk * 32 + quad * 8;
      float4 c0 = *(const float4*)(cp + hb);
      float4 c1 = *(const float4*)(cp + hb + 4);
      float4 s0 = *(const float4*)(sp + hb);
      float4 s1 = *(const float4*)(sp + hb + 4);
      float cc[8] = {c0.x, c0.y, c0.z, c0.w, c1.x, c1.y, c1.z, c1.w};
      float ss[8] = {s0.x, s0.y, s0.z, s0.w, s1.x, s1.y, s1.z, s1.w};
#pragma unroll
      for (int j = 0; j < 8; ++j) {
        float a = qv[kk * 8 + j];
        float bb = qv[(kk + 2) * 8 + j];
        qfrag[kk][j] = (short)f2bf(a * cc[j] - bb * ss[j]);
        qfrag[kk + 2][j] = (short)f2bf(bb * cc[j] + a * ss[j]);
      }
    }
  }

  f32x4 o[8];
#pragma unroll
  for (int i = 0; i < 8; ++i) o[i] = (f32x4){0.f, 0.f, 0.f, 0.f};
  float run_m[4] = {-1e30f, -1e30f, -1e30f, -1e30f};
  float run_l[4] = {0.f, 0.f, 0.f, 0.f};

  const int kst = tid >> 4;            // K stage: t row 0..15 (+16i)
  const int ksh = (tid & 15) << 3;     // K stage: h offset
  const int vst = (tid & 7) << 3;      // V stage: t offset
  const int vsh = tid >> 3;            // V stage: h row 0..31 (+32i)
  const size_t kbase0 = ((size_t)(b * 2048) * 8 + kh) * 128;
  const size_t vbase0 = ((size_t)(b * 8 + kh)) * 128 * 2048;
  u16* plw = pl + wave * 16 * TP;

  uint4 kr[4], vr[4];
  auto load_chunk = [&](int c) {
#pragma unroll
    for (int i = 0; i < 4; ++i)
      kr[i] = *(const uint4*)(kt + kbase0 + (size_t)(c * 64 + kst + i * 16) * 1024 + ksh);
#pragma unroll
    for (int i = 0; i < 4; ++i)
      vr[i] = *(const uint4*)(vtg + vbase0 + (size_t)(vsh + i * 32) * 2048 + c * 64 + vst);
  };
  load_chunk(0);

  for (int c = 0; c <= qt; ++c) {
    __syncthreads();
#pragma unroll
    for (int i = 0; i < 4; ++i) *(uint4*)(kl + (kst + i * 16) * KP + ksh) = kr[i];
#pragma unroll
    for (int i = 0; i < 4; ++i) *(uint4*)(vt + (vsh + i * 32) * TP + vst) = vr[i];
    __syncthreads();
    if (c < qt) load_chunk(c + 1);   // prefetch next chunk; latency hides behind compute

    // ---- QK^T : 4 n-tiles of 16 kv positions
    f32x4 s[4];
#pragma unroll
    for (int nt = 0; nt < 4; ++nt) {
      s[nt] = (f32x4){0.f, 0.f, 0.f, 0.f};
#pragma unroll
      for (int kk = 0; kk < 4; ++kk) {
        bf16x8 bf = *(const bf16x8*)(kl + (nt * 16 + l16) * KP + kk * 32 + quad * 8);
        s[nt] = __builtin_amdgcn_mfma_f32_16x16x32_bf16(qfrag[kk], bf, s[nt], 0, 0, 0);
      }
    }
    // ---- causal mask on the diagonal chunk
    if (c == qt) {
      int rbase = wave * 16 + quad * 4;
#pragma unroll
      for (int nt = 0; nt < 4; ++nt)
#pragma unroll
        for (int r = 0; r < 4; ++r)
          if (nt * 16 + l16 > rbase + r) s[nt][r] = -1e30f;
    }
    // ---- online softmax (row = (quad,reg); reduce across l16 lanes)
    float p[4][4];
#pragma unroll
    for (int r = 0; r < 4; ++r) {
      float cm = fmaxf(fmaxf(s[0][r], s[1][r]), fmaxf(s[2][r], s[3][r]));
#pragma unroll
      for (int off = 1; off < 16; off <<= 1) cm = fmaxf(cm, __shfl_xor(cm, off));
      float newm = fmaxf(run_m[r], cm);
      float alpha = __expf(run_m[r] - newm);
      float rs = 0.f;
#pragma unroll
      for (int nt = 0; nt < 4; ++nt) {
        float pv = __expf(s[nt][r] - newm);
        p[nt][r] = pv;
        rs += pv;
      }
#pragma unroll
      for (int off = 1; off < 16; off <<= 1) rs += __shfl_xor(rs, off);
      run_l[r] = run_l[r] * alpha + rs;
      run_m[r] = newm;
#pragma unroll
      for (int ht = 0; ht < 8; ++ht) o[ht][r] *= alpha;
    }
    // ---- P -> per-wave LDS [m][t] (bf16)
#pragma unroll
    for (int nt = 0; nt < 4; ++nt)
#pragma unroll
      for (int r = 0; r < 4; ++r)
        plw[(quad * 4 + r) * TP + nt * 16 + l16] = f2bf_trunc(p[nt][r]);
    // ---- PV : O[16 x 128] += P[16 x 64] * V[64 x 128]
#pragma unroll
    for (int kk = 0; kk < 2; ++kk) {
      bf16x8 af = *(const bf16x8*)(plw + l16 * TP + kk * 32 + quad * 8);
#pragma unroll
      for (int ht = 0; ht < 8; ++ht) {
        bf16x8 bf = *(const bf16x8*)(vt + (ht * 16 + l16) * TP + kk * 32 + quad * 8);
        o[ht] = __builtin_amdgcn_mfma_f32_16x16x32_bf16(af, bf, o[ht], 0, 0, 0);
      }
    }
  }

  // ---- epilogue: normalize + store
  float inv_l[4];
#pragma unroll
  for (int r = 0; r < 4; ++r) inv_l[r] = 1.0f / run_l[r];
#pragma unroll
  for (int r = 0; r < 4; ++r) {
    int row = qbase + wave * 16 + quad * 4 + r;
    size_t base = ((size_t)(b * 2048 + row)) * 4096 + (size_t)head * 128 + l16;
#pragma unroll
    for (int ht = 0; ht < 8; ++ht)
      y2[base + ht * 16] = f2bf(o[ht][r] * inv_l[r]);
  }
}

// ---------------------------------------------------------------- launch
extern "C" void kernel_launch(void* const* d_in, const int* in_sizes, int n_in,
                              void* d_out, int out_size, void* d_ws, size_t ws_size,
                              hipStream_t stream) {
  const float* x = (const float*)d_in[0];
  const float* wq = (const float*)d_in[1];
  const float* wk = (const float*)d_in[2];
  const float* wv = (const float*)d_in[3];
  const float* wo = (const float*)d_in[4];
  const float* sinT = (const float*)d_in[6];
  const float* cosT = (const float*)d_in[7];
  float* out = (float*)d_out;

  char* ws = (char*)d_ws;
  size_t off = 0;
  auto alloc = [&](size_t bytes) -> void* {
    void* p = ws + off;
    off += (bytes + 255) & ~(size_t)255;
    return p;
  };
  u16* xb  = (u16*)alloc(16777216ull * 2);  // x bf16 [4096,4096]
  u16* wqT = (u16*)alloc(16777216ull * 2);  // [4096(rkh),4096(d)]
  u16* wkT = (u16*)alloc(4194304ull * 2);   // [1024,4096]; together with wvT = wkvT [2048,4096]
  u16* wvT = (u16*)alloc(4194304ull * 2);   //   (contiguous: 8388608 B is 256-aligned)
  u16* woT = (u16*)alloc(16777216ull * 2);  // [4096(d),4096(rkh)]
  u16* qf  = (u16*)alloc(16777216ull * 2);  // [b,s,(r,k,h)]
  u16* kvf = (u16*)alloc(8388608ull * 2);   // [b*s,2048]: K heads | V heads
  u16* ktb = (u16*)alloc(4194304ull * 2);   // roped+scaled K, [b,s,(k,h)]
  u16* y2  = (u16*)alloc(16777216ull * 2);  // [b,s,(r,k,h)]
  (void)wvT;

  dim3 tb(32, 8);
  f32_to_bf16_k<<<dim3(16384), 256, 0, stream>>>(x, xb, 4194304);
  transpose_to_bf16<<<dim3(128, 128), tb, 0, stream>>>(wq, wqT, 4096, 4096);
  transpose_to_bf16<<<dim3(32, 128), tb, 0, stream>>>(wk, wkT, 4096, 1024);
  transpose_to_bf16<<<dim3(32, 128), tb, 0, stream>>>(wv, wvT, 4096, 1024);
  transpose_to_bf16<<<dim3(128, 128), tb, 0, stream>>>(wo, woT, 4096, 4096);

  gemm128<<<dim3(32, 32), 256, 0, stream>>>(xb, wqT, qf, 4096, 4096, 4096, 1);
  gemm128<<<dim3(16, 32), 256, 0, stream>>>(xb, wkT, kvf, 4096, 2048, 4096, 1);  // K+V fused

  rope_k_kernel<<<dim3(16384), 256, 0, stream>>>(kvf, ktb, sinT, cosT);

  u16* vtg = wkT;  // wkvT dead after KV gemm; reuse as V^T [b,kh,h,t] (8.39 MB fits exactly)
  transpose_v<<<dim3(64, 4, 16), tb, 0, stream>>>(kvf, vtg);

  attn_mfma<<<dim3(32, 32, 2), 256, 0, stream>>>(qf, ktb, vtg, sinT, cosT, y2);

  gemm128<<<dim3(32, 32), 256, 0, stream>>>(y2, woT, out, 4096, 4096, 4096, 0);
}